// Round 1
// baseline (544.028 us; speedup 1.0000x reference)
//
#include <hip/hip_runtime.h>
#include <cstdint>

typedef unsigned short u16;
typedef __attribute__((ext_vector_type(8))) short short8;   // 8 bf16 = 4 VGPRs (MFMA A/B frag)
typedef __attribute__((ext_vector_type(4))) float f32x4;    // MFMA C/D frag / float4 store

// round-to-nearest-even fp32 -> bf16 bits (finite normals; no NaN path needed)
__device__ __forceinline__ u16 f2bf(float f) {
  unsigned u = __float_as_uint(f);
  u += 0x7fffu + ((u >> 16) & 1u);
  return (u16)(u >> 16);
}

// ---- kernel 1: x = inputs / ||inputs||  (fp32 -> bf16), one block per row ----
__global__ void norm_cast_kernel(const float* __restrict__ in, u16* __restrict__ xb) {
  const int row = blockIdx.x;
  const int t = threadIdx.x;           // 256 threads, D = 256
  float v = in[row * 256 + t];
  float s = v * v;
  #pragma unroll
  for (int off = 32; off >= 1; off >>= 1) s += __shfl_xor(s, off, 64);
  __shared__ float wsum[4];
  if ((t & 63) == 0) wsum[t >> 6] = s;
  __syncthreads();
  const float tot = wsum[0] + wsum[1] + wsum[2] + wsum[3];
  xb[row * 256 + t] = f2bf(v * rsqrtf(tot));
}

// ---- kernel 2: features fp32 -> bf16 bank in workspace ----
__global__ void cvt_bf16_kernel(const float4* __restrict__ in, ushort4* __restrict__ out, int n4) {
  const int i = blockIdx.x * 256 + threadIdx.x;
  if (i < n4) {
    float4 v = in[i];
    out[i] = make_ushort4(f2bf(v.x), f2bf(v.y), f2bf(v.z), f2bf(v.w));
  }
}

// ---- kernel 3: C[M,N] = (X[M,K] . F[N,K]^T) * 20, bf16 MFMA ----
// BM=BN=128, BK=64 (4 K-iters -> half the barrier drains of BK=32), 256 thr = 4 waves 2x2,
// each wave a 64x64 quadrant of 4x4 16x16x32 MFMAs, 2 k-substeps per K-iter.
// LDS tiles are [row][slot] with slot = chunk ^ (row&7) (T2 both-sides swizzle, rule #21):
// global_load_lds dest stays LINEAR; the SOURCE k-chunk is inverse-swizzled per lane; reads
// XOR the same involution -> uniform 8 words/bank (conflict-free) instead of 16-way at 128B stride.
template <bool CONVB>
__global__ __launch_bounds__(256) void gemm_kernel(
    const u16* __restrict__ A,      // x bf16 [1024][256]
    const u16* __restrict__ Bbf,    // features bf16 [N][256]   (CONVB == false)
    const float* __restrict__ Bfp,  // features fp32 [N][256]   (CONVB == true)
    float* __restrict__ C, int Nn, int NWG)
{
  __shared__ u16 lds[2][128 * 64];   // A tile 16 KB, B tile 16 KB

  const int tid  = threadIdx.x;
  const int wave = tid >> 6;
  const int lane = tid & 63;

  // T1 bijective XCD swizzle: NWG = 8 * n_tiles (divisible by 8). XCD x gets a contiguous
  // wg chunk; wg%8 = m-tile (fast) -> the 8 blocks sharing a B-tile land on ONE XCD's L2.
  const int cpx = NWG >> 3;
  const int wg  = ((int)blockIdx.x & 7) * cpx + ((int)blockIdx.x >> 3);
  const int m0  = (wg & 7) * 128;
  const int n0  = (wg >> 3) * 128;

  const int wm = (wave & 1) * 64;
  const int wn = (wave >> 1) * 64;

  f32x4 acc[4][4] = {};

  // staging: round r covers rows r*32..r*32+31; thread t -> row r*32+(t>>3), LDS slot t&7,
  // global chunk = slot ^ (row&7)  (8 threads of a row still cover one contiguous 128 B span)
  const int srow_in = tid >> 3;                         // 0..31 within a round
  const int schunk  = ((tid & 7) ^ ((tid >> 3) & 7)) * 8; // swizzled k-element offset

  const int fr = lane & 15;        // fragment row (m for A, n for B)
  const int q  = lane >> 4;        // quarter-wave -> k chunk

  for (int k0 = 0; k0 < 256; k0 += 64) {
    // ---- stage A: 128 rows x 64 k = 16 KB, 4 rounds of 256x16B ----
    #pragma unroll
    for (int r = 0; r < 4; ++r) {
      const u16* gp = A + (size_t)(m0 + r * 32 + srow_in) * 256 + k0 + schunk;
      u16* lp = lds[0] + (r * 32 + wave * 8) * 64;   // wave-uniform; HW adds lane*16B
      __builtin_amdgcn_global_load_lds(
          (const __attribute__((address_space(1))) void*)gp,
          (__attribute__((address_space(3))) void*)lp, 16, 0, 0);
    }
    // ---- stage B ----
    if constexpr (!CONVB) {
      #pragma unroll
      for (int r = 0; r < 4; ++r) {
        int grow = n0 + r * 32 + srow_in;
        if (grow >= Nn) grow = Nn - 1;               // clamp tail; stores masked later
        const u16* gp = Bbf + (size_t)grow * 256 + k0 + schunk;
        u16* lp = lds[1] + (r * 32 + wave * 8) * 64;
        __builtin_amdgcn_global_load_lds(
            (const __attribute__((address_space(1))) void*)gp,
            (__attribute__((address_space(3))) void*)lp, 16, 0, 0);
      }
    } else {
      // on-the-fly fp32 -> bf16 into swizzled slots: 1024 slots, 4 rounds of 256
      #pragma unroll
      for (int r = 0; r < 4; ++r) {
        const int idx = r * 256 + tid;
        const int row = idx >> 3;
        const int cs  = idx & 7;                 // LDS slot
        const int cg  = cs ^ (row & 7);          // global chunk
        int grow = n0 + row;
        if (grow >= Nn) grow = Nn - 1;
        const float* src = Bfp + (size_t)grow * 256 + k0 + cg * 8;
        float4 v0 = *(const float4*)src;
        float4 v1 = *(const float4*)(src + 4);
        short8 o;
        o[0] = (short)f2bf(v0.x); o[1] = (short)f2bf(v0.y);
        o[2] = (short)f2bf(v0.z); o[3] = (short)f2bf(v0.w);
        o[4] = (short)f2bf(v1.x); o[5] = (short)f2bf(v1.y);
        o[6] = (short)f2bf(v1.z); o[7] = (short)f2bf(v1.w);
        *(short8*)(&lds[1][row * 64 + cs * 8]) = o;
      }
    }
    __syncthreads();   // compiler emits s_waitcnt vmcnt(0) lgkmcnt(0) before s_barrier

    // ---- fragments + MFMA, 2 k-substeps of 32 ----
    #pragma unroll
    for (int ks = 0; ks < 2; ++ks) {
      const int cl = ks * 4 + q;                 // logical k chunk 0..7
      short8 af[4], bf[4];
      #pragma unroll
      for (int i = 0; i < 4; ++i) {
        const int sl = (cl ^ (fr & 7)) * 8;      // swizzled slot (row&7 == fr&7: wm,i*16 mult of 16)
        af[i] = *(const short8*)(&lds[0][(wm + i * 16 + fr) * 64 + sl]);
        bf[i] = *(const short8*)(&lds[1][(wn + i * 16 + fr) * 64 + sl]);
      }
      #pragma unroll
      for (int mi = 0; mi < 4; ++mi)
        #pragma unroll
        for (int ni = 0; ni < 4; ++ni)
          acc[mi][ni] = __builtin_amdgcn_mfma_f32_16x16x32_bf16(af[mi], bf[ni], acc[mi][ni], 0, 0, 0);
    }
    __syncthreads();   // protects LDS for next stage; after last iter it frees LDS for epilogue
  }

  // ---- epilogue: per-wave private LDS bounce -> coalesced dwordx4 stores ----
  // C/D layout: col = lane&15, row = (lane>>4)*4 + reg. Direct stores would be 64 x dword
  // (64 B segments); bouncing a 16x64 quadrant slab (stride 68: 16B-aligned, 2-way writes,
  // uniform reads) gives 16 x dwordx4 with 256 B contiguity per quarter-wave.
  float* slab = (float*)lds + wave * 2048;      // 8 KB per wave, no cross-wave sync needed
  const int rquad = q * 4;
  #pragma unroll
  for (int mi = 0; mi < 4; ++mi) {
    #pragma unroll
    for (int ni = 0; ni < 4; ++ni)
      #pragma unroll
      for (int i = 0; i < 4; ++i)
        slab[(rquad + i) * 68 + ni * 16 + fr] = acc[mi][ni][i] * 20.0f;   // 1/TEMP
    // compiler inserts the lgkmcnt wait (provable alias within lds)
    #pragma unroll
    for (int rr = 0; rr < 4; ++rr) {
      const int r16 = rr * 4 + q;
      f32x4 v = *(const f32x4*)(slab + r16 * 68 + fr * 4);
      const int m = m0 + wm + mi * 16 + r16;
      const int n = n0 + wn + fr * 4;
      if (n + 4 <= Nn) {
        *(f32x4*)(C + (size_t)m * Nn + n) = v;
      } else {
        #pragma unroll
        for (int e = 0; e < 4; ++e)
          if (n + e < Nn) C[(size_t)m * Nn + n + e] = v[e];
      }
    }
  }
}

extern "C" void kernel_launch(void* const* d_in, const int* in_sizes, int n_in,
                              void* d_out, int out_size, void* d_ws, size_t ws_size,
                              hipStream_t stream) {
  const float* inputs   = (const float*)d_in[0];
  // d_in[1] (targets) is dead code for the forward output
  const float* features = (const float*)d_in[2];
  float* out = (float*)d_out;

  const int Bv = in_sizes[1];            // 1024
  const int Dv = in_sizes[0] / Bv;       // 256
  const int Nn = in_sizes[2] / Dv;       // 100000

  u16* xb = (u16*)d_ws;                                         // bf16 x: B*D
  const size_t x_bytes = ((size_t)Bv * Dv * 2 + 255) & ~(size_t)255;
  u16* fb = (u16*)((char*)d_ws + x_bytes);                      // bf16 features: N*D
  const size_t f_bytes = (size_t)Nn * Dv * 2;
  const bool fits = ws_size >= x_bytes + f_bytes;

  norm_cast_kernel<<<dim3(Bv), dim3(256), 0, stream>>>(inputs, xb);

  const int ntn = (Nn + 127) / 128;
  const int nwg = (Bv / 128) * ntn;      // 8 * 782 = 6256, divisible by 8
  if (fits) {
    const int n4 = (Nn * Dv) / 4;
    cvt_bf16_kernel<<<dim3((n4 + 255) / 256), dim3(256), 0, stream>>>(
        (const float4*)features, (ushort4*)fb, n4);
    gemm_kernel<false><<<dim3(nwg), dim3(256), 0, stream>>>(xb, fb, nullptr, out, Nn, nwg);
  } else {
    gemm_kernel<true><<<dim3(nwg), dim3(256), 0, stream>>>(xb, nullptr, features, out, Nn, nwg);
  }
}

// Round 2
// 525.957 us; speedup vs baseline: 1.0344x; 1.0344x over previous
//
#include <hip/hip_runtime.h>
#include <cstdint>

typedef unsigned short u16;
typedef __attribute__((ext_vector_type(8))) short short8;   // 8 bf16 = 4 VGPRs (MFMA A/B frag)
typedef __attribute__((ext_vector_type(4))) float f32x4;    // MFMA C/D frag

// round-to-nearest-even fp32 -> bf16 bits (finite normals; no NaN path needed)
__device__ __forceinline__ u16 f2bf(float f) {
  unsigned u = __float_as_uint(f);
  u += 0x7fffu + ((u >> 16) & 1u);
  return (u16)(u >> 16);
}

// ---- kernel 1: x = inputs / ||inputs||  (fp32 -> bf16), one block per row ----
__global__ void norm_cast_kernel(const float* __restrict__ in, u16* __restrict__ xb) {
  const int row = blockIdx.x;
  const int t = threadIdx.x;           // 256 threads, D = 256
  float v = in[row * 256 + t];
  float s = v * v;
  #pragma unroll
  for (int off = 32; off >= 1; off >>= 1) s += __shfl_xor(s, off, 64);
  __shared__ float wsum[4];
  if ((t & 63) == 0) wsum[t >> 6] = s;
  __syncthreads();
  const float tot = wsum[0] + wsum[1] + wsum[2] + wsum[3];
  xb[row * 256 + t] = f2bf(v * rsqrtf(tot));
}

// ---- kernel 2: features fp32 -> bf16 bank in workspace ----
__global__ void cvt_bf16_kernel(const float4* __restrict__ in, ushort4* __restrict__ out, int n4) {
  const int i = blockIdx.x * 256 + threadIdx.x;
  if (i < n4) {
    float4 v = in[i];
    out[i] = make_ushort4(f2bf(v.x), f2bf(v.y), f2bf(v.z), f2bf(v.w));
  }
}

// stage 64 rows x 256 k (32 KB bf16) into lbuf via global_load_lds w=16.
// LDS layout: [row][slot], slot holds global chunk (slot ^ (row&7))  (T2 both-sides swizzle,
// rule #21: linear LDS dest + inverse-swizzled global SOURCE + swizzled read).
// round r, wave w -> segment seg=r*4+w = 1 KB = rows {2seg, 2seg+1}; HW adds lane*16B.
__device__ __forceinline__ void stage_rows(const u16* __restrict__ base, int row0, int maxrow,
                                           u16* lbuf, int wave, int lane) {
  const int rl0 = lane >> 5;          // row within segment
  const int cl  = lane & 31;          // LDS 16B-chunk slot
  #pragma unroll
  for (int r = 0; r < 8; ++r) {
    const int seg   = r * 4 + wave;
    const int row_l = seg * 2 + rl0;
    int grow = row0 + row_l;
    if (grow > maxrow) grow = maxrow;                 // clamp tail rows (stores masked later)
    const int cg = cl ^ (row_l & 7);                  // inverse-swizzled source chunk
    const u16* gp = base + (size_t)grow * 256 + cg * 8;
    u16* lp = lbuf + seg * 512;                       // wave-uniform base
    __builtin_amdgcn_global_load_lds(
        (const __attribute__((address_space(1))) void*)gp,
        (__attribute__((address_space(3))) void*)lp, 16, 0, 0);
  }
}

// ---- kernel 3: C[M,N] = (X . F^T) * 20, bf16 MFMA, persistent-B-in-registers ----
// Shape-specialized: K=256 tiny, N huge. Block = 1 n-tile (BN=128) x 4 m-tiles (BM=64).
// B frags (full K) live in 128 VGPRs, loaded once; A double-buffered in 2x32 KB LDS.
// One barrier per m-tile (vs 2 per 32-MFMA in the old BK-loop). LDS 64 KB -> 2 blocks/CU.
template <bool CONVB>
__global__ __launch_bounds__(256, 2) void gemm_kernel(
    const u16* __restrict__ A,      // x bf16 [M][256]
    const u16* __restrict__ Bbf,    // features bf16 [N][256]   (CONVB == false)
    const float* __restrict__ Bfp,  // features fp32 [N][256]   (CONVB == true)
    float* __restrict__ C, int Nn, int Mv, int NWG, int MSPL)
{
  __shared__ u16 buf0[64 * 256];    // 32 KB
  __shared__ u16 buf1[64 * 256];    // 32 KB

  const int tid  = threadIdx.x;
  const int wave = tid >> 6;
  const int lane = tid & 63;

  // T1 bijective XCD swizzle (m204 formula). Consecutive wg in a chunk = the MSPL m-split
  // blocks of one n-tile -> they share the B-tile in that XCD's L2.
  const int q8 = NWG >> 3, r8 = NWG & 7;
  const int xcd = (int)blockIdx.x & 7;
  const int wg  = (xcd < r8 ? xcd * (q8 + 1) : r8 * (q8 + 1) + (xcd - r8) * q8)
                + ((int)blockIdx.x >> 3);
  const int ntile  = wg / MSPL;
  const int msplit = wg % MSPL;
  const int n0 = ntile * 128;

  const int fr = lane & 15;         // fragment row (m for A, n for B)
  const int q  = lane >> 4;         // quarter -> k chunk / row quad
  const int wm = (wave >> 1) * 32;  // wave tile: 32m x 64n
  const int wn = (wave & 1) * 64;

  // ---- setup: B tile (128 rows x K=256) -> buf0 (rows 0-63) + buf1 (rows 64-127) ----
  if constexpr (!CONVB) {
    stage_rows(Bbf, n0,      Nn - 1, buf0, wave, lane);
    stage_rows(Bbf, n0 + 64, Nn - 1, buf1, wave, lane);
  } else {
    #pragma unroll
    for (int h = 0; h < 2; ++h) {
      u16* dst = h ? buf1 : buf0;
      #pragma unroll
      for (int r = 0; r < 8; ++r) {
        const int idx   = r * 256 + tid;
        const int row_l = idx >> 5;
        const int cl    = idx & 31;
        const int cg    = cl ^ (row_l & 7);
        int grow = n0 + h * 64 + row_l;
        if (grow >= Nn) grow = Nn - 1;
        const float* sp = Bfp + (size_t)grow * 256 + cg * 8;
        float4 v0 = *(const float4*)sp;
        float4 v1 = *(const float4*)(sp + 4);
        short8 o;
        o[0] = (short)f2bf(v0.x); o[1] = (short)f2bf(v0.y);
        o[2] = (short)f2bf(v0.z); o[3] = (short)f2bf(v0.w);
        o[4] = (short)f2bf(v1.x); o[5] = (short)f2bf(v1.y);
        o[6] = (short)f2bf(v1.z); o[7] = (short)f2bf(v1.w);
        *(short8*)(dst + row_l * 256 + cl * 8) = o;
      }
    }
  }
  __syncthreads();   // B staged (vmcnt/lgkm drained by compiler)

  // ---- B fragments -> registers: breg[ni][ks], 32 x short8 = 128 VGPRs ----
  short8 breg[4][8];
  {
    const u16* bsrc = (wave & 1) ? buf1 : buf0;   // wn=64 waves read rows 64-127
    #pragma unroll
    for (int ni = 0; ni < 4; ++ni) {
      const int row_l = ni * 16 + fr;
      #pragma unroll
      for (int ks = 0; ks < 8; ++ks) {
        const int cs = ((ks * 4 + q) ^ (fr & 7)) * 8;   // swizzled slot (row_l&7 == fr&7)
        breg[ni][ks] = *(const short8*)(bsrc + row_l * 256 + cs);
      }
    }
  }
  __syncthreads();   // all waves done reading B before buffers are reused for A

  // ---- A m-tile 0 -> buf0 ----
  stage_rows(A, msplit * 256, Mv - 1, buf0, wave, lane);
  __syncthreads();

  // ---- m-loop: 4 tiles of 64 rows, double-buffered ----
  #pragma unroll
  for (int it = 0; it < 4; ++it) {
    if (it < 3)
      stage_rows(A, msplit * 256 + (it + 1) * 64, Mv - 1, (it & 1) ? buf0 : buf1, wave, lane);
    const u16* cb = (it & 1) ? buf1 : buf0;

    f32x4 acc[2][4] = {};
    #pragma unroll
    for (int ks = 0; ks < 8; ++ks) {
      short8 af[2];
      #pragma unroll
      for (int mi = 0; mi < 2; ++mi) {
        const int row_l = wm + mi * 16 + fr;
        const int cs = ((ks * 4 + q) ^ (fr & 7)) * 8;
        af[mi] = *(const short8*)(cb + row_l * 256 + cs);
      }
      #pragma unroll
      for (int mi = 0; mi < 2; ++mi)
        #pragma unroll
        for (int ni = 0; ni < 4; ++ni)
          acc[mi][ni] = __builtin_amdgcn_mfma_f32_16x16x32_bf16(af[mi], breg[ni][ks], acc[mi][ni], 0, 0, 0);
    }

    // store: C/D layout col=lane&15, row=(lane>>4)*4+reg. Per row the 4 ni-stores cover
    // 64 consecutive cols -> 64 B segments, regionally dense (L2 write-combines).
    const int mbase = msplit * 256 + it * 64 + wm + q * 4;
    #pragma unroll
    for (int mi = 0; mi < 2; ++mi) {
      #pragma unroll
      for (int ni = 0; ni < 4; ++ni) {
        const int n = n0 + wn + ni * 16 + fr;
        if (n < Nn) {
          float* cp = C + (size_t)(mbase + mi * 16) * Nn + n;
          #pragma unroll
          for (int i = 0; i < 4; ++i)
            cp[(size_t)i * Nn] = acc[mi][ni][i] * 20.0f;   // 1/TEMP
        }
      }
    }
    if (it < 3) __syncthreads();   // next A stage drained; protects buf overwrite
  }
}

extern "C" void kernel_launch(void* const* d_in, const int* in_sizes, int n_in,
                              void* d_out, int out_size, void* d_ws, size_t ws_size,
                              hipStream_t stream) {
  const float* inputs   = (const float*)d_in[0];
  // d_in[1] (targets) is dead code for the forward output
  const float* features = (const float*)d_in[2];
  float* out = (float*)d_out;

  const int Bv = in_sizes[1];            // 1024
  const int Dv = in_sizes[0] / Bv;       // 256
  const int Nn = in_sizes[2] / Dv;       // 100000

  u16* xb = (u16*)d_ws;                                         // bf16 x: B*D
  const size_t x_bytes = ((size_t)Bv * Dv * 2 + 255) & ~(size_t)255;
  u16* fb = (u16*)((char*)d_ws + x_bytes);                      // bf16 features: N*D
  const size_t f_bytes = (size_t)Nn * Dv * 2;
  const bool fits = ws_size >= x_bytes + f_bytes;

  norm_cast_kernel<<<dim3(Bv), dim3(256), 0, stream>>>(inputs, xb);

  const int ntiles = (Nn + 127) / 128;   // 782
  const int mspl   = Bv / 256;           // 4 m-split blocks (each 4 tiles of 64 rows)
  const int nwg    = ntiles * mspl;      // 3128 = 8 * 391 (exact XCD chunks)

  if (fits) {
    const int n4 = (Nn * Dv) / 4;
    cvt_bf16_kernel<<<dim3((n4 + 255) / 256), dim3(256), 0, stream>>>(
        (const float4*)features, (ushort4*)fb, n4);
    gemm_kernel<false><<<dim3(nwg), dim3(256), 0, stream>>>(
        xb, fb, nullptr, out, Nn, Bv, nwg, mspl);
  } else {
    gemm_kernel<true><<<dim3(nwg), dim3(256), 0, stream>>>(
        xb, nullptr, features, out, Nn, Bv, nwg, mspl);
  }
}